// Round 6
// baseline (436.237 us; speedup 1.0000x reference)
//
#include <hip/hip_runtime.h>
#include <math.h>

#define T_TOKENS 16384
#define NEXP     64
#define KDIM     4096
#define SLICES   16                  // K slices of 256
#define KSL      256
#define TGB      512                 // tokens per block (group)
#define TTILE    32                  // tokens per tile

typedef _Float16 f16;
typedef f16   f16x2 __attribute__((ext_vector_type(2)));
typedef f16   f16x8 __attribute__((ext_vector_type(8)));
typedef float f32x4 __attribute__((ext_vector_type(4)));

// split 8 fp32 -> packed fp16 hi (uint4) and lo*2^11 (uint4)
__device__ __forceinline__ void split8(const float v[8], uint4* ho, uint4* lo) {
    unsigned hu[4], lu[4];
    #pragma unroll
    for (int p = 0; p < 4; ++p) {
        f16x2 h2, l2;
#if __has_builtin(__builtin_amdgcn_cvt_pkrtz)
        h2 = __builtin_bit_cast(f16x2, __builtin_amdgcn_cvt_pkrtz(v[2*p], v[2*p+1]));
#else
        h2.x = (f16)v[2*p]; h2.y = (f16)v[2*p+1];
#endif
        float r0 = (v[2*p]   - (float)h2.x) * 2048.0f;
        float r1 = (v[2*p+1] - (float)h2.y) * 2048.0f;
#if __has_builtin(__builtin_amdgcn_cvt_pkrtz)
        l2 = __builtin_bit_cast(f16x2, __builtin_amdgcn_cvt_pkrtz(r0, r1));
#else
        l2.x = (f16)r0; l2.y = (f16)r1;
#endif
        hu[p] = __builtin_bit_cast(unsigned, h2);
        lu[p] = __builtin_bit_cast(unsigned, l2);
    }
    *ho = make_uint4(hu[0], hu[1], hu[2], hu[3]);
    *lo = make_uint4(lu[0], lu[1], lu[2], lu[3]);
}

__device__ __forceinline__ f16x8 asf16x8(uint4 u) {
    return __builtin_bit_cast(f16x8, u);
}

// ---------------------------------------------------------------------------
// K0: zero the 4 MB logits accumulator in d_ws (ws arrives poisoned).
// ---------------------------------------------------------------------------
__global__ void k_zero(float4* __restrict__ p) {
    p[blockIdx.x * 256 + threadIdx.x] = (float4){0.f, 0.f, 0.f, 0.f};
}

// ---------------------------------------------------------------------------
// K1: persistent-W logits. Grid = SLICES x (T/TGB) = 16 x 32 = 512 blocks
// (exactly 2/CU, tail-free), 512 thr (8 waves: mt = wid>>2 token half,
// nt = wid&3 expert tile). Each block:
//   - stages its W[64 exp][256 k] slice as f16 hi/lo MFMA B-frags into 64 KB
//     LDS ONCE (ONE barrier in the whole kernel; removes the 32-64 per-round
//     barrier+vmcnt(0) drains that capped R3-R5 at 112-126 us),
//   - then streams 16 tiles of 32 tokens with ZERO barriers: x global->reg in
//     A-frag order (lane's 8 elems = 8 contiguous floats of one row; a wave's
//     instr pair fully consumes 16 cache lines), in-reg split8, MFMA vs the
//     read-only LDS W, and 4 fire-and-forget global_atomic_add f32 per lane.
// Frag layouts (verified R0-R5):
//   A/B lane l elem j: row = tile*16+(l&15), k = s*32+(l>>4)*8+j
//   C/D: col(expert) = lane&15, row(token) = (lane>>4)*4+rr
//   B-frag LDS byte = (s*8 + fmt*4 + nt)*1024 + lane*16  (64 KB, conflict-free)
// logits accumulate x64-scaled: 64*logit = sum_slices(acc_hh + acc_lo/2048).
// ---------------------------------------------------------------------------
__global__ __launch_bounds__(512, 4) void k_logits(
    const float* __restrict__ x, const float* __restrict__ W,
    float* __restrict__ logits)
{
    __shared__ __align__(16) unsigned char Bs[65536];

    const int tid  = threadIdx.x;
    const int wid  = tid >> 6;
    const int lane = tid & 63;
    const int slice = blockIdx.x & (SLICES - 1);
    const int tg    = blockIdx.x >> 4;
    const int k0    = slice * KSL;
    const int mt    = wid >> 2;           // token half of tile (16 tok)
    const int nt    = wid & 3;            // expert tile (16 exp)

    // ---- one-time W staging: thread covers 32 contiguous k of one expert ----
    {
        const int erow = tid >> 3;        // expert 0..63
        const int s    = tid & 7;         // which k32 step (32 floats each)
        const int e15  = erow & 15;
        const int wnt  = erow >> 4;
        const float* wp = W + (size_t)erow * KDIM + k0 + s * 32;
        float4 wv[8];
        #pragma unroll
        for (int q = 0; q < 8; ++q) wv[q] = *(const float4*)(wp + q * 4);
        #pragma unroll
        for (int g = 0; g < 4; ++g) {     // j3 = g
            float v[8] = { wv[2*g].x * 64.f,   wv[2*g].y * 64.f,
                           wv[2*g].z * 64.f,   wv[2*g].w * 64.f,
                           wv[2*g+1].x * 64.f, wv[2*g+1].y * 64.f,
                           wv[2*g+1].z * 64.f, wv[2*g+1].w * 64.f };
            uint4 ho, lo;
            split8(v, &ho, &lo);
            const int u = (s * 8 + wnt) * 1024 + (g * 16 + e15) * 16;
            *(uint4*)(Bs + u)        = ho;   // fmt=0
            *(uint4*)(Bs + u + 4096) = lo;   // fmt=1
        }
    }
    __syncthreads();   // the ONLY barrier

    // ---- token-tile stream: no barriers, atomics are fire-and-forget ----
    const float* xbase = x + (size_t)(tg * TGB + mt * 16 + (lane & 15)) * KDIM
                       + k0 + ((lane >> 4) << 3);
    const int bread = nt * 1024 + lane * 16;

    for (int tile = 0; tile < TGB / TTILE; ++tile) {   // 16 tiles
        const float* xt = xbase + (size_t)tile * TTILE * KDIM;
        // issue all 16 x loads up front (in-order vmcnt pipelining)
        float4 xv[16];
        #pragma unroll
        for (int s = 0; s < 8; ++s) {
            xv[2*s]   = *(const float4*)(xt + s * 32);
            xv[2*s+1] = *(const float4*)(xt + s * 32 + 4);
        }
        f32x4 ahh = (f32x4){0.f, 0.f, 0.f, 0.f};
        f32x4 alo = (f32x4){0.f, 0.f, 0.f, 0.f};
        #pragma unroll
        for (int s = 0; s < 8; ++s) {
            float v[8] = { xv[2*s].x,   xv[2*s].y,   xv[2*s].z,   xv[2*s].w,
                           xv[2*s+1].x, xv[2*s+1].y, xv[2*s+1].z, xv[2*s+1].w };
            uint4 ahu, alu;
            split8(v, &ahu, &alu);
            f16x8 ah = asf16x8(ahu);
            f16x8 al = asf16x8(alu);
            f16x8 bh = asf16x8(*(const uint4*)(Bs + s * 8192 + bread));
            f16x8 bl = asf16x8(*(const uint4*)(Bs + s * 8192 + bread + 4096));
            ahh = __builtin_amdgcn_mfma_f32_16x16x32_f16(ah, bh, ahh, 0, 0, 0);
            alo = __builtin_amdgcn_mfma_f32_16x16x32_f16(ah, bl, alo, 0, 0, 0);
            alo = __builtin_amdgcn_mfma_f32_16x16x32_f16(al, bh, alo, 0, 0, 0);
        }
        float* lrow = logits
            + (size_t)(tg * TGB + tile * TTILE + mt * 16 + (lane >> 4) * 4) * NEXP
            + nt * 16 + (lane & 15);
        #pragma unroll
        for (int rr = 0; rr < 4; ++rr)
            atomicAdd(lrow + rr * NEXP, ahh[rr] + alo[rr] * (1.0f / 2048.0f));
    }
}

// ---------------------------------------------------------------------------
// K2: finalize — per token read 64 summed logits, top-2, softmax, pack out.
// ---------------------------------------------------------------------------
__global__ __launch_bounds__(256) void k_topk(
    const float* __restrict__ logits, float* __restrict__ out)
{
    const int t = blockIdx.x * 256 + threadIdx.x;
    const float4* lp = (const float4*)(logits + (size_t)t * NEXP);
    float m1 = -INFINITY, m2 = -INFINITY;
    int i1 = 0, i2 = 0;
    #pragma unroll
    for (int q = 0; q < 16; ++q) {
        float4 v4 = lp[q];
        #pragma unroll
        for (int j = 0; j < 4; ++j) {
            float v = (j == 0) ? v4.x : (j == 1) ? v4.y : (j == 2) ? v4.z : v4.w;
            int e = q * 4 + j;
            if (v > m1)      { m2 = m1; i2 = i1; m1 = v; i1 = e; }
            else if (v > m2) { m2 = v; i2 = e; }
        }
    }
    float e2 = __expf((m2 - m1) * (1.0f / 64.0f));  // undo x64 W scale
    float denom = 1.f + e2;
    out[t * 2 + 0] = 1.f / denom;
    out[t * 2 + 1] = e2 / denom;
    out[2 * T_TOKENS + t * 2 + 0] = (float)i1;
    out[2 * T_TOKENS + t * 2 + 1] = (float)i2;
}

extern "C" void kernel_launch(void* const* d_in, const int* in_sizes, int n_in,
                              void* d_out, int out_size, void* d_ws, size_t ws_size,
                              hipStream_t stream) {
    const float* x = (const float*)d_in[0];
    const float* W = (const float*)d_in[1];
    float* logits = (float*)d_ws;   // 4 MB scratch; ws poison is unconditional

    k_zero<<<(T_TOKENS * NEXP) / (256 * 4), 256, 0, stream>>>((float4*)logits);
    k_logits<<<SLICES * (T_TOKENS / TGB), 512, 0, stream>>>(x, W, logits);
    k_topk<<<T_TOKENS / 256, 256, 0, stream>>>(logits, (float*)d_out);
}